// Round 2
// baseline (573.466 us; speedup 1.0000x reference)
//
#include <hip/hip_runtime.h>
#include <hip/hip_bf16.h>

#define Bc 4
#define Tc 16
#define Nc 1024
#define Ec 16384
#define FIN 128
#define Hc 256
#define FFc 1024
#define NHc 8
#define Lc 2
#define HDc 32
#define Gc 64
#define EPSc 1e-5f

typedef __bf16 v8bf __attribute__((ext_vector_type(8)));
typedef float v4f __attribute__((ext_vector_type(4)));

#define GLOAD_LDS16(gp, lp) \
    __builtin_amdgcn_global_load_lds((const __attribute__((address_space(1))) void*)(gp), \
                                     (__attribute__((address_space(3))) void*)(lp), 16, 0, 0)

// ---------------- W pack: Wcat[256][256]=[Wl1;Wr1] -> MFMA B-frag order, bf16 hi+lo ----------------
__global__ void pack_w_kernel(const float* __restrict__ Wl, const float* __restrict__ Wr,
                              __bf16* __restrict__ pH, __bf16* __restrict__ pL) {
    int bid = blockIdx.x;            // 0..127 = kc*16+nt
    int t = threadIdx.x;             // 512
    int lane = t >> 3, j = t & 7;
    int kc = bid >> 4, nt = bid & 15;
    int k = kc * 32 + ((lane >> 4) << 3) + j;
    int n = nt * 16 + (lane & 15);
    float w = (k < 128) ? Wl[(size_t)k * Hc + n] : Wr[(size_t)(k - 128) * Hc + n];
    __bf16 hi = (__bf16)w;
    __bf16 lo = (__bf16)(w - (float)hi);
    pH[bid * 512 + t] = hi;
    pL[bid * 512 + t] = lo;
}

// ---------------- per graph: invdeg, cw, CSR(off,elist ushort), zero uv. 1024 thr ----------------
__global__ __launch_bounds__(1024) void csr_kernel(
        const int* __restrict__ ei, float* __restrict__ invdeg, float* __restrict__ cw,
        int* __restrict__ off, unsigned short* __restrict__ elist, float* __restrict__ uv) {
    __shared__ int degs[Nc];
    __shared__ float inv[Nc];
    __shared__ float cl[Nc];
    __shared__ int wsum[16];
    int g = blockIdx.x, t = threadIdx.x;   // 1024 threads
    const int* src = ei + (size_t)g * 2 * Ec;
    const int* dst = src + Ec;
    if (t < 512) uv[g * 512 + t] = 0.f;
    degs[t] = 0; cl[t] = 0.f;
    __syncthreads();
    for (int e = t; e < Ec; e += 1024) atomicAdd(&degs[dst[e] & (Nc - 1)], 1);
    __syncthreads();
    float iv = 1.0f / fmaxf((float)degs[t], 1.0f);
    inv[t] = iv;
    invdeg[g * Nc + t] = iv;
    __syncthreads();
    for (int e = t; e < Ec; e += 1024) atomicAdd(&cl[src[e] & (Nc - 1)], inv[dst[e] & (Nc - 1)]);
    __syncthreads();
    cw[g * Nc + t] = cl[t];
    // wave-level inclusive scan of degs (16 waves of 64)
    int own = degs[t];
    int lane = t & 63, wv = t >> 6;
    int val = own;
#pragma unroll
    for (int ofs = 1; ofs < 64; ofs <<= 1) {
        int v = __shfl_up(val, ofs, 64);
        if (lane >= ofs) val += v;
    }
    if (lane == 63) wsum[wv] = val;
    __syncthreads();
    if (wv == 0 && lane < 16) {
        int wval = wsum[lane];
#pragma unroll
        for (int ofs = 1; ofs < 16; ofs <<= 1) {
            int v = __shfl_up(wval, ofs, 64);
            if (lane >= ofs) wval += v;
        }
        wsum[lane] = wval;
    }
    __syncthreads();
    int incl = val + ((wv > 0) ? wsum[wv - 1] : 0);
    int excl = incl - own;
    off[g * 1032 + t] = excl;
    if (t == 1023) off[g * 1032 + Nc] = incl;
    degs[t] = excl;                      // cursors
    __syncthreads();
    for (int e = t; e < Ec; e += 1024) {
        int d = dst[e] & (Nc - 1);
        int slot = atomicAdd(&degs[d], 1);
        elist[(size_t)g * Ec + slot] = (unsigned short)(src[e] & (Nc - 1));
    }
}

// ---------------- SAGE layer1 + reduce: async-gather pipeline -> MFMA hi/lo -> u,v ----------------
// LDS layout (floats):
//   aggL [32*132]           0..4223     (skewed, row stride 132)
//   xL   [32*128]        4224..8319     (linear, global_load_lds staged)
//   stage[8][4][256]     8320..16511    (per-wave 4 slots x 1KB)
//   lu   [256]          16512..16767
//   lv   [256]          16768..17023
//   invS [32]           17024..17055
//   elS  [1028 ushort]  17056..17569
__global__ __launch_bounds__(512) void sage_kernel(
        const float* __restrict__ x, const unsigned short* __restrict__ elist,
        const int* __restrict__ off, const float* __restrict__ invdeg,
        const float* __restrict__ cw, const __bf16* __restrict__ pH,
        const __bf16* __restrict__ pL, const float* __restrict__ bias,
        float* __restrict__ uv) {
    __shared__ __align__(16) float smem[17570];
    float* aggL = smem;                    // stride 132
    float* xL = smem + 4224;               // stride 128
    float* stage = smem + 8320;
    float* lu = smem + 16512;
    float* lv = smem + 16768;
    float* invS = smem + 17024;
    unsigned short* elS = (unsigned short*)(smem + 17056);

    int tid = threadIdx.x;
    int bid = blockIdx.x;
    // XCD swizzle: bid = cc*64 + g  => all 32 blocks of graph g share bid%8 (same XCD L2)
    int g = bid & 63, cc = bid >> 6, r0 = cc * 32;
    const unsigned short* el = elist + (size_t)g * Ec;
    const float* xg = x + (size_t)g * Nc * FIN;
    int wv = tid >> 6, lane = tid & 63;

    // ---- stage xL rows via async (2 instrs per wave: rows 4wv+2k, +1) ----
#pragma unroll
    for (int k = 0; k < 2; ++k) {
        int rr = 4 * wv + 2 * k;
        const float* gp = xg + (size_t)(r0 + rr) * FIN + lane * 4;
        GLOAD_LDS16(gp, &xL[rr * FIN]);
    }

    // ---- block-uniform CSR window ----
    int ob = g * 1032 + r0;
    int eb0 = off[ob];
    int eend = off[ob + 32];
    int cnt = eend - eb0;
    bool fb = (cnt > 1024);              // fallback (statistically impossible; safety)

    if (tid < 256) { lu[tid] = 0.f; lv[tid] = 0.f; }
    if (tid < 32) invS[tid] = invdeg[g * Nc + r0 + tid];
    if (!fb) {
        for (int i = tid; i < cnt + 2; i += 512) elS[i] = el[eb0 + i];
    }
    // wave row-range boundaries (uniform per wave)
    int rw0 = r0 + 4 * wv;
    int oA  = off[g * 1032 + rw0];
    int oE1 = off[g * 1032 + rw0 + 1];
    int oE2 = off[g * 1032 + rw0 + 2];
    int oE3 = off[g * 1032 + rw0 + 3];
    int oE4 = off[g * 1032 + rw0 + 4];
    __syncthreads();   // elS/invS visible; drains xL asyncs too

    if (!fb) {
        // ---- phase A: per-wave async-gather pipeline over contiguous edge stream ----
        float* myst = &stage[wv * 1024];
        int ebase = oA;
        int nE = oE4 - oA;
        int np = (nE + 1) >> 1;          // pairs of edges
        float ax = 0.f, ay = 0.f;
        int r = 0;
        int bnd = oE1;

        auto ISSUE = [&](int p) {
            int e0 = ebase + 2 * p;
            int s = elS[e0 - eb0 + (lane >> 5)] & (Nc - 1);
            const float* gp = xg + (size_t)s * FIN + (lane & 31) * 4;
            GLOAD_LDS16(gp, myst + (p & 3) * 256);
        };
        auto WOUT = [&]() {
            float iv = invS[4 * wv + r];
            int arow = 4 * wv + r;
            *(float2*)&aggL[arow * 132 + 2 * lane] = make_float2(ax * iv, ay * iv);
            ax = 0.f; ay = 0.f;
            ++r;
            bnd = (r == 1) ? oE2 : (r == 2) ? oE3 : oE4;
        };

        if (np > 0) ISSUE(0);
        if (np > 1) ISSUE(1);
        if (np > 2) ISSUE(2);
        int e = ebase;
        for (int p = 0; p < np; ++p) {
            int rem = np - 1 - p;        // newest pairs allowed outstanding
            if (rem >= 2)      asm volatile("s_waitcnt vmcnt(2)" ::: "memory");
            else if (rem == 1) asm volatile("s_waitcnt vmcnt(1)" ::: "memory");
            else               asm volatile("s_waitcnt vmcnt(0)" ::: "memory");
            const float* sp = myst + (p & 3) * 256;
#pragma unroll
            for (int j = 0; j < 2; ++j) {
                while (r < 4 && e >= bnd) WOUT();
                if (e < oE4) {
                    float2 v = *(const float2*)&sp[j * 128 + 2 * lane];
                    ax += v.x; ay += v.y;
                }
                ++e;
            }
            if (p + 3 < np) ISSUE(p + 3);
        }
        while (r < 4) WOUT();
    } else {
        // ---- fallback: original per-(row,chunk) register gather ----
        int lr = tid >> 4, ch = tid & 15;
        int n = r0 + lr;
        int o0 = off[g * 1032 + n], o1 = off[g * 1032 + n + 1];
        float4 a0 = make_float4(0.f, 0.f, 0.f, 0.f);
        float4 a1 = make_float4(0.f, 0.f, 0.f, 0.f);
        const float* xc = xg + ch * 8;
        for (int e2 = o0; e2 < o1; ++e2) {
            const float4* xp = (const float4*)(xc + (size_t)el[e2] * FIN);
            float4 v0 = xp[0], v1 = xp[1];
            a0.x += v0.x; a0.y += v0.y; a0.z += v0.z; a0.w += v0.w;
            a1.x += v1.x; a1.y += v1.y; a1.z += v1.z; a1.w += v1.w;
        }
        float iv = invdeg[g * Nc + n];
        float* dp = &aggL[lr * 132 + ch * 8];
        dp[0] = a0.x * iv; dp[1] = a0.y * iv; dp[2] = a0.z * iv; dp[3] = a0.w * iv;
        dp[4] = a1.x * iv; dp[5] = a1.y * iv; dp[6] = a1.z * iv; dp[7] = a1.w * iv;
    }
    __syncthreads();

    // ---- phase B: 8 waves: mt = w&1 (16-row tile), nh = w>>1 (4 n-tiles each) ----
    int w = wv, quad = lane >> 4;
    int mt = w & 1, nh = w >> 1;
    int lrow = mt * 16 + (lane & 15);
    v4f acc[4];
#pragma unroll
    for (int i = 0; i < 4; ++i) acc[i] = (v4f)0.f;
    for (int kc = 0; kc < 8; ++kc) {
        const float* ap = (kc < 4) ? &aggL[lrow * 132 + kc * 32 + quad * 8]
                                   : &xL[lrow * 128 + (kc - 4) * 32 + quad * 8];
        float4 f0 = *(const float4*)ap;
        float4 f1 = *(const float4*)(ap + 4);
        float av[8] = {f0.x, f0.y, f0.z, f0.w, f1.x, f1.y, f1.z, f1.w};
        v8bf aH, aL;
#pragma unroll
        for (int j = 0; j < 8; ++j) {
            __bf16 hb = (__bf16)av[j];
            aH[j] = hb;
            aL[j] = (__bf16)(av[j] - (float)hb);
        }
#pragma unroll
        for (int i = 0; i < 4; ++i) {
            int nt = nh * 4 + i;
            v8bf bH = *(const v8bf*)(pH + ((size_t)(kc * 16 + nt) * 64 + lane) * 8);
            v8bf bL = *(const v8bf*)(pL + ((size_t)(kc * 16 + nt) * 64 + lane) * 8);
            acc[i] = __builtin_amdgcn_mfma_f32_16x16x32_bf16(aH, bH, acc[i], 0, 0, 0);
            acc[i] = __builtin_amdgcn_mfma_f32_16x16x32_bf16(aL, bH, acc[i], 0, 0, 0);
            acc[i] = __builtin_amdgcn_mfma_f32_16x16x32_bf16(aH, bL, acc[i], 0, 0, 0);
        }
    }

    // epilogue: bias+relu; u (cw-weighted) / v column sums. C/D: col=lane&15, row=quad*4+r
    float c4[4];
    int nb = g * Nc + r0 + mt * 16 + quad * 4;
#pragma unroll
    for (int rr = 0; rr < 4; ++rr) c4[rr] = cw[nb + rr];
#pragma unroll
    for (int i = 0; i < 4; ++i) {
        int col = (nh * 4 + i) * 16 + (lane & 15);
        float bcol = bias[col];
        float su = 0.f, sv = 0.f;
#pragma unroll
        for (int rr = 0; rr < 4; ++rr) {
            float val = fmaxf(acc[i][rr] + bcol, 0.f);
            sv += val;
            su += c4[rr] * val;
        }
        su += __shfl_xor(su, 16); sv += __shfl_xor(sv, 16);
        su += __shfl_xor(su, 32); sv += __shfl_xor(sv, 32);
        if (quad == 0) { atomicAdd(&lu[col], su); atomicAdd(&lv[col], sv); }
    }
    __syncthreads();
    if (tid < 256) {
        atomicAdd(&uv[g * 512 + tid], lu[tid]);
        atomicAdd(&uv[g * 512 + 256 + tid], lv[tid]);
    }
}

// ---------------- emb = u/N @ Wl2 + bl2 + v/N @ Wr2. 512 thr, K split 2 ----------------
__global__ __launch_bounds__(512) void emb_kernel(
        const float* __restrict__ uv, const float* __restrict__ Wl2,
        const float* __restrict__ bl2, const float* __restrict__ Wr2,
        float* __restrict__ h) {
    __shared__ float s[512];
    __shared__ float r2[512];
    int g = blockIdx.x, tid = threadIdx.x;
    s[tid] = uv[g * 512 + tid] * (1.0f / Nc);
    __syncthreads();
    int col = tid & 255, p = tid >> 8;
    float val = 0.f;
    if (p == 0) { for (int k = 0; k < 256; ++k) val += s[k] * Wl2[(size_t)k * Hc + col]; }
    else        { for (int k = 0; k < 256; ++k) val += s[256 + k] * Wr2[(size_t)k * Hc + col]; }
    r2[tid] = val;
    __syncthreads();
    if (tid < 256) h[g * Hc + tid] = bl2[tid] + r2[tid] + r2[tid + 256];
}

// ---------------- qkv: token x seg, 512 thr, K split 2 ----------------
__global__ __launch_bounds__(512) void qkv_kernel(
        const float* __restrict__ h, const float* __restrict__ Wqkv,
        const float* __restrict__ bqkv, float* __restrict__ qkv, int l) {
    __shared__ float hr[256];
    __shared__ float r2[512];
    int bid = blockIdx.x;            // 64 tokens * 3 segs
    int gi = bid / 3, seg = bid % 3;
    int tid = threadIdx.x;
    if (tid < 256) hr[tid] = h[gi * Hc + tid];
    __syncthreads();
    int col = seg * 256 + (tid & 255);
    int half = tid >> 8;
    const float* W = Wqkv + (size_t)l * Hc * 768;
    float val = 0.f;
    int k0 = half * 128;
    for (int k = 0; k < 128; ++k) val += hr[k0 + k] * W[(size_t)(k0 + k) * 768 + col];
    r2[tid] = val;
    __syncthreads();
    if (tid < 256) qkv[gi * 768 + col] = bqkv[(size_t)l * 768 + col] + r2[tid] + r2[tid + 256];
}

// ---------------- attn + proj + ln1 -> h1buf. per-token, 512 thr, proj K-split 2 ----------------
#define KVS 516
__global__ __launch_bounds__(512) void apl_kernel(
        const float* __restrict__ h, const float* __restrict__ qkvg,
        const float* __restrict__ Wo, const float* __restrict__ bo,
        const float* __restrict__ s1, const float* __restrict__ b1ln,
        float* __restrict__ h1buf, int l) {
    __shared__ float kv[16 * KVS];
    __shared__ float q[256];
    __shared__ float sc[8][17];
    __shared__ float ctx[256];
    __shared__ float r2[512];
    __shared__ float red[256];
    int t = blockIdx.x, tid = threadIdx.x;
    int b = t >> 4;
    const float* qb = qkvg + (size_t)(b * 16) * 768;
    for (int i = tid; i < 8192; i += 512) {
        int j = i >> 9, d = i & 511;
        kv[j * KVS + d] = qb[(size_t)j * 768 + 256 + d];
    }
    if (tid < 256) q[tid] = qkvg[(size_t)t * 768 + tid];
    __syncthreads();
    if (tid < 128) {
        int hd = tid >> 4, j = tid & 15;
        float s = 0.f;
#pragma unroll
        for (int d = 0; d < 32; ++d) s += q[hd * 32 + d] * kv[j * KVS + hd * 32 + d];
        sc[hd][j] = s * 0.17677669529663687f;
    }
    __syncthreads();
    if (tid < 8) {
        float m = sc[tid][0];
        for (int j = 1; j < 16; ++j) m = fmaxf(m, sc[tid][j]);
        float e[16], sum = 0.f;
        for (int j = 0; j < 16; ++j) { e[j] = expf(sc[tid][j] - m); sum += e[j]; }
        float inv = 1.0f / sum;
        for (int j = 0; j < 16; ++j) sc[tid][j] = e[j] * inv;
    }
    __syncthreads();
    if (tid < 256) {
        int hd = tid >> 5, d = tid & 31;
        float o = 0.f;
#pragma unroll
        for (int j = 0; j < 16; ++j) o += sc[hd][j] * kv[j * KVS + 256 + hd * 32 + d];
        ctx[tid] = o;
    }
    __syncthreads();
    // proj: K split 2 over 512 threads
    int col = tid & 255, half = tid >> 8;
    const float* W = Wo + (size_t)l * 65536;
    float pv = 0.f;
    int k0 = half * 128;
    for (int k = 0; k < 128; ++k) pv += ctx[k0 + k] * W[(size_t)(k0 + k) * 256 + col];
    r2[tid] = pv;
    __syncthreads();
    float val = 0.f;
    if (tid < 256) {
        val = h[(size_t)t * 256 + tid] + bo[(size_t)l * 256 + tid] + r2[tid] + r2[tid + 256];
        red[tid] = val;
    }
    __syncthreads();
    for (int s = 128; s > 0; s >>= 1) { if (tid < s) red[tid] += red[tid + s]; __syncthreads(); }
    float m1 = red[0] * (1.0f / 256.0f);
    __syncthreads();
    float d1 = val - m1;
    if (tid < 256) red[tid] = d1 * d1;
    __syncthreads();
    for (int s = 128; s > 0; s >>= 1) { if (tid < s) red[tid] += red[tid + s]; __syncthreads(); }
    float v1 = red[0] * (1.0f / 256.0f);
    if (tid < 256)
        h1buf[(size_t)t * 256 + tid] =
            d1 * rsqrtf(v1 + EPSc) * s1[(size_t)l * 256 + tid] + b1ln[(size_t)l * 256 + tid];
}

// ---------------- ffn1: (token, colgroup) grid 256, 512 thr, K split 2 ----------------
__global__ __launch_bounds__(512) void ffn1_kernel(
        const float* __restrict__ h1buf, const float* __restrict__ W1,
        const float* __restrict__ bf1, float* __restrict__ fL, int l) {
    __shared__ float hr[256];
    __shared__ float r2[512];
    int bid = blockIdx.x;
    int t = bid >> 2, cg = bid & 3;
    int tid = threadIdx.x;
    if (tid < 256) hr[tid] = h1buf[(size_t)t * 256 + tid];
    __syncthreads();
    int col = cg * 256 + (tid & 255);
    int half = tid >> 8;
    const float* W = W1 + (size_t)l * 262144;
    float val = 0.f;
    int k0 = half * 128;
    for (int k = 0; k < 128; ++k) val += hr[k0 + k] * W[(size_t)(k0 + k) * 1024 + col];
    r2[tid] = val;
    __syncthreads();
    if (tid < 256)
        fL[(size_t)t * 1024 + col] = fmaxf(bf1[(size_t)l * 1024 + col] + r2[tid] + r2[tid + 256], 0.f);
}

// ---------------- ffn2 + ln2 (+fc): per token, 1024 thr, K split 4 ----------------
__global__ __launch_bounds__(1024) void ffn2_ln_kernel(
        float* __restrict__ h, const float* __restrict__ h1buf, const float* __restrict__ fL,
        const float* __restrict__ W2, const float* __restrict__ bf2,
        const float* __restrict__ s2, const float* __restrict__ b2ln,
        const float* __restrict__ fcW, const float* __restrict__ fcb,
        float* __restrict__ out, int l, int last) {
    __shared__ float fs[1024];
    __shared__ float r4[1024];
    __shared__ float red[256];
    int t = blockIdx.x, tid = threadIdx.x;
    fs[tid] = fL[(size_t)t * 1024 + tid];
    __syncthreads();
    int col = tid & 255, kq = tid >> 8;
    const float* W = W2 + (size_t)l * 262144;
    float p = 0.f;
    int k0 = kq * 256;
    for (int k = 0; k < 256; ++k) p += fs[k0 + k] * W[(size_t)(k0 + k) * 256 + col];
    r4[tid] = p;
    __syncthreads();
    float val = 0.f;
    if (tid < 256) {
        val = h1buf[(size_t)t * 256 + tid] + bf2[(size_t)l * 256 + tid]
            + r4[tid] + r4[tid + 256] + r4[tid + 512] + r4[tid + 768];
        red[tid] = val;
    }
    __syncthreads();
    for (int s = 128; s > 0; s >>= 1) { if (tid < s) red[tid] += red[tid + s]; __syncthreads(); }
    float m2 = red[0] * (1.0f / 256.0f);
    __syncthreads();
    float d2 = (tid < 256) ? (val - m2) : 0.f;
    if (tid < 256) red[tid] = d2 * d2;
    __syncthreads();
    for (int s = 128; s > 0; s >>= 1) { if (tid < s) red[tid] += red[tid + s]; __syncthreads(); }
    float var2 = red[0] * (1.0f / 256.0f);
    float hn = 0.f;
    if (tid < 256) {
        hn = d2 * rsqrtf(var2 + EPSc) * s2[(size_t)l * 256 + tid] + b2ln[(size_t)l * 256 + tid];
        h[(size_t)t * 256 + tid] = hn;
    }
    if (last && (t & 15) == 15) {
        __syncthreads();
        if (tid < 256) red[tid] = hn;
        __syncthreads();
        if (tid < 10) {
            int b = t >> 4;
            float fv = fcb[tid];
            for (int k = 0; k < 256; ++k) fv += red[k] * fcW[(size_t)k * 10 + tid];
            out[b * 10 + tid] = fv;
        }
    }
}

extern "C" void kernel_launch(void* const* d_in, const int* in_sizes, int n_in,
                              void* d_out, int out_size, void* d_ws, size_t ws_size,
                              hipStream_t stream) {
    (void)in_sizes; (void)n_in; (void)out_size; (void)ws_size;
    const float* x    = (const float*)d_in[0];
    const int*   ei   = (const int*)d_in[1];
    const float* s1Wl = (const float*)d_in[2];
    const float* s1bl = (const float*)d_in[3];
    const float* s1Wr = (const float*)d_in[4];
    const float* s2Wl = (const float*)d_in[5];
    const float* s2bl = (const float*)d_in[6];
    const float* s2Wr = (const float*)d_in[7];
    const float* Wqkv = (const float*)d_in[8];
    const float* bqkv = (const float*)d_in[9];
    const float* Wo   = (const float*)d_in[10];
    const float* bo   = (const float*)d_in[11];
    const float* ln1s = (const float*)d_in[12];
    const float* ln1b = (const float*)d_in[13];
    const float* W1   = (const float*)d_in[14];
    const float* b1   = (const float*)d_in[15];
    const float* W2   = (const float*)d_in[16];
    const float* b2   = (const float*)d_in[17];
    const float* ln2s = (const float*)d_in[18];
    const float* ln2b = (const float*)d_in[19];
    const float* fcW  = (const float*)d_in[20];
    const float* fcb  = (const float*)d_in[21];

    // workspace layout (total ~3.87 MB)
    char* ws = (char*)d_ws;
    __bf16*         packWH = (__bf16*)(ws + 0);          // 131072
    __bf16*         packWL = (__bf16*)(ws + 131072);     // 131072
    float*          invdeg = (float*)(ws + 262144);      // 262144
    float*          cw     = (float*)(ws + 524288);      // 262144
    int*            off    = (int*)(ws + 786432);        // 264192
    unsigned short* elist  = (unsigned short*)(ws + 1050624); // 2097152
    float*          uv     = (float*)(ws + 3147776);     // 131072
    float*          h      = (float*)(ws + 3278848);     // 65536
    float*          qkvg   = (float*)(ws + 3344384);     // 196608
    float*          h1buf  = (float*)(ws + 3540992);     // 65536
    float*          fLbuf  = (float*)(ws + 3606528);     // 262144
                                                         // end = 3868672

    pack_w_kernel<<<128, 512, 0, stream>>>(s1Wl, s1Wr, packWH, packWL);
    csr_kernel<<<Gc, 1024, 0, stream>>>(ei, invdeg, cw, off, elist, uv);
    sage_kernel<<<Gc * 32, 512, 0, stream>>>(x, elist, off, invdeg, cw, packWH, packWL, s1bl, uv);
    emb_kernel<<<Gc, 512, 0, stream>>>(uv, s2Wl, s2bl, s2Wr, h);
    for (int l = 0; l < Lc; ++l) {
        qkv_kernel<<<Gc * 3, 512, 0, stream>>>(h, Wqkv, bqkv, qkvg, l);
        apl_kernel<<<Gc, 512, 0, stream>>>(h, qkvg, Wo, bo, ln1s, ln1b, h1buf, l);
        ffn1_kernel<<<Gc * 4, 512, 0, stream>>>(h1buf, W1, b1, fLbuf, l);
        ffn2_ln_kernel<<<Gc, 1024, 0, stream>>>(h, h1buf, fLbuf, W2, b2, ln2s, ln2b,
                                                fcW, fcb, (float*)d_out, l, l == Lc - 1);
    }
}

// Round 5
// 315.045 us; speedup vs baseline: 1.8203x; 1.8203x over previous
//
#include <hip/hip_runtime.h>
#include <hip/hip_bf16.h>

#define Bc 4
#define Tc 16
#define Nc 1024
#define Ec 16384
#define FIN 128
#define Hc 256
#define FFc 1024
#define NHc 8
#define Lc 2
#define HDc 32
#define Gc 64
#define EPSc 1e-5f

typedef __bf16 v8bf __attribute__((ext_vector_type(8)));
typedef float v4f __attribute__((ext_vector_type(4)));

// ---------------- W pack: Wcat[256][256]=[Wl1;Wr1] -> MFMA B-frag order, bf16 hi+lo ----------------
__global__ void pack_w_kernel(const float* __restrict__ Wl, const float* __restrict__ Wr,
                              __bf16* __restrict__ pH, __bf16* __restrict__ pL) {
    int bid = blockIdx.x;            // 0..127 = kc*16+nt
    int t = threadIdx.x;             // 512
    int lane = t >> 3, j = t & 7;
    int kc = bid >> 4, nt = bid & 15;
    int k = kc * 32 + ((lane >> 4) << 3) + j;
    int n = nt * 16 + (lane & 15);
    float w = (k < 128) ? Wl[(size_t)k * Hc + n] : Wr[(size_t)(k - 128) * Hc + n];
    __bf16 hi = (__bf16)w;
    __bf16 lo = (__bf16)(w - (float)hi);
    pH[bid * 512 + t] = hi;
    pL[bid * 512 + t] = lo;
}

// ---------------- per graph: invdeg, cw, CSR(off,elist ushort), zero uv. 1024 thr ----------------
__global__ __launch_bounds__(1024) void csr_kernel(
        const int* __restrict__ ei, float* __restrict__ invdeg, float* __restrict__ cw,
        int* __restrict__ off, unsigned short* __restrict__ elist, float* __restrict__ uv) {
    __shared__ int degs[Nc];
    __shared__ float inv[Nc];
    __shared__ float cl[Nc];
    __shared__ int wsum[16];
    int g = blockIdx.x, t = threadIdx.x;   // 1024 threads
    const int* src = ei + (size_t)g * 2 * Ec;
    const int* dst = src + Ec;
    if (t < 512) uv[g * 512 + t] = 0.f;
    degs[t] = 0; cl[t] = 0.f;
    __syncthreads();
    for (int e = t; e < Ec; e += 1024) atomicAdd(&degs[dst[e] & (Nc - 1)], 1);
    __syncthreads();
    float iv = 1.0f / fmaxf((float)degs[t], 1.0f);
    inv[t] = iv;
    invdeg[g * Nc + t] = iv;
    __syncthreads();
    for (int e = t; e < Ec; e += 1024) atomicAdd(&cl[src[e] & (Nc - 1)], inv[dst[e] & (Nc - 1)]);
    __syncthreads();
    cw[g * Nc + t] = cl[t];
    // wave-level inclusive scan of degs (16 waves of 64)
    int own = degs[t];
    int lane = t & 63, wv = t >> 6;
    int val = own;
#pragma unroll
    for (int ofs = 1; ofs < 64; ofs <<= 1) {
        int v = __shfl_up(val, ofs, 64);
        if (lane >= ofs) val += v;
    }
    if (lane == 63) wsum[wv] = val;
    __syncthreads();
    if (wv == 0 && lane < 16) {
        int wval = wsum[lane];
#pragma unroll
        for (int ofs = 1; ofs < 16; ofs <<= 1) {
            int v = __shfl_up(wval, ofs, 64);
            if (lane >= ofs) wval += v;
        }
        wsum[lane] = wval;
    }
    __syncthreads();
    int incl = val + ((wv > 0) ? wsum[wv - 1] : 0);
    int excl = incl - own;
    off[g * 1032 + t] = excl;
    if (t == 1023) off[g * 1032 + Nc] = incl;
    degs[t] = excl;                      // cursors
    __syncthreads();
    for (int e = t; e < Ec; e += 1024) {
        int d = dst[e] & (Nc - 1);
        int slot = atomicAdd(&degs[d], 1);
        elist[(size_t)g * Ec + slot] = (unsigned short)(src[e] & (Nc - 1));
    }
}

// ---------------- SAGE layer1 + reduce: 4-deep reg-rotation gather -> MFMA hi/lo -> u,v ----------
__global__ __launch_bounds__(512) void sage_kernel(
        const float* __restrict__ x, const unsigned short* __restrict__ elist,
        const int* __restrict__ off, const float* __restrict__ invdeg,
        const float* __restrict__ cw, const __bf16* __restrict__ pH,
        const __bf16* __restrict__ pL, const float* __restrict__ bias,
        float* __restrict__ uv) {
    __shared__ float aggL[32 * 132];     // stride 132 (4-float row skew)
    __shared__ float xL[32 * 132];
    __shared__ float lu[256], lv[256];
    __shared__ unsigned short elS[1024];
    int tid = threadIdx.x;
    int bid = blockIdx.x;
    // XCD swizzle: bid = cc*64 + g  => all 32 blocks of graph g share bid%8 (same XCD L2)
    int g = bid & 63, cc = bid >> 6, r0 = cc * 32;
    const unsigned short* el = elist + (size_t)g * Ec;
    const float* xg = x + (size_t)g * Nc * FIN;
    if (tid < 256) { lu[tid] = 0.f; lv[tid] = 0.f; }

    // block-uniform CSR window; stage edge indices to LDS (cnt <= 1024 statistically certain)
    int ob = g * 1032 + r0;
    int eb0 = off[ob];
    int cnt = off[ob + 32] - eb0;
    bool fb = (cnt > 1024);              // safety fallback: read el directly from global
    if (!fb) {
        for (int i = tid; i < cnt; i += 512) elS[i] = el[eb0 + i];
    }
    // stage own-row x tile (float4)
    for (int i = tid; i < 1024; i += 512) {
        int lr = i >> 5, kq = i & 31;
        *(float4*)&xL[lr * 132 + kq * 4] = *(const float4*)&xg[(size_t)(r0 + lr) * FIN + kq * 4];
    }
    __syncthreads();

    // phase A: one (row, 8-dim chunk) per thread; 4-deep cross-iteration load rotation.
    // Per-dim fp32 adds in ascending-edge order (bit-identical to verified baseline).
    {
        int lr = tid >> 4, ch = tid & 15;
        int n = r0 + lr;
        int o0 = off[g * 1032 + n], o1 = off[g * 1032 + n + 1];
        int m = o1 - o0;
        const float* xc = xg + ch * 8;
        const unsigned short* EP = fb ? el : elS;
        int eb = fb ? 0 : eb0;           // EP[e - eb] == el[e]
        float4 a0 = make_float4(0.f, 0.f, 0.f, 0.f);
        float4 a1 = make_float4(0.f, 0.f, 0.f, 0.f);
        float4 p00, p01, p10, p11, p20, p21, p30, p31;

#define LOADP(P0, P1, E) { const float4* xp_ = \
            (const float4*)(xc + (size_t)EP[(E) - eb] * FIN); \
            P0 = xp_[0]; P1 = xp_[1]; }
#define ACC(P0, P1) { a0.x += P0.x; a0.y += P0.y; a0.z += P0.z; a0.w += P0.w; \
                      a1.x += P1.x; a1.y += P1.y; a1.z += P1.z; a1.w += P1.w; }

        if (m > 0) LOADP(p00, p01, o0 + 0);
        if (m > 1) LOADP(p10, p11, o0 + 1);
        if (m > 2) LOADP(p20, p21, o0 + 2);
        if (m > 3) LOADP(p30, p31, o0 + 3);
        int i = 0;
        for (; i + 4 <= m; i += 4) {
            ACC(p00, p01); if (i + 4 < m) LOADP(p00, p01, o0 + i + 4);
            ACC(p10, p11); if (i + 5 < m) LOADP(p10, p11, o0 + i + 5);
            ACC(p20, p21); if (i + 6 < m) LOADP(p20, p21, o0 + i + 6);
            ACC(p30, p31); if (i + 7 < m) LOADP(p30, p31, o0 + i + 7);
        }
        if (i + 0 < m) ACC(p00, p01);
        if (i + 1 < m) ACC(p10, p11);
        if (i + 2 < m) ACC(p20, p21);
        if (i + 3 < m) ACC(p30, p31);
#undef LOADP
#undef ACC

        float iv = invdeg[g * Nc + n];
        float* dp = &aggL[lr * 132 + ch * 8];
        dp[0] = a0.x * iv; dp[1] = a0.y * iv; dp[2] = a0.z * iv; dp[3] = a0.w * iv;
        dp[4] = a1.x * iv; dp[5] = a1.y * iv; dp[6] = a1.z * iv; dp[7] = a1.w * iv;
    }
    __syncthreads();

    // phase B: 8 waves: mt = w&1 (16-row tile), nh = w>>1 (4 n-tiles each)
    int w = tid >> 6, lane = tid & 63, quad = lane >> 4;
    int mt = w & 1, nh = w >> 1;
    int lrow = mt * 16 + (lane & 15);
    v4f acc[4];
#pragma unroll
    for (int i = 0; i < 4; ++i) acc[i] = (v4f)0.f;
    for (int kc = 0; kc < 8; ++kc) {
        const float* ap = (kc < 4) ? &aggL[lrow * 132 + kc * 32 + quad * 8]
                                   : &xL[lrow * 132 + (kc - 4) * 32 + quad * 8];
        float4 f0 = *(const float4*)ap;
        float4 f1 = *(const float4*)(ap + 4);
        float av[8] = {f0.x, f0.y, f0.z, f0.w, f1.x, f1.y, f1.z, f1.w};
        v8bf aH, aL;
#pragma unroll
        for (int j = 0; j < 8; ++j) {
            __bf16 hb = (__bf16)av[j];
            aH[j] = hb;
            aL[j] = (__bf16)(av[j] - (float)hb);
        }
#pragma unroll
        for (int i = 0; i < 4; ++i) {
            int nt = nh * 4 + i;
            v8bf bH = *(const v8bf*)(pH + ((size_t)(kc * 16 + nt) * 64 + lane) * 8);
            v8bf bL = *(const v8bf*)(pL + ((size_t)(kc * 16 + nt) * 64 + lane) * 8);
            acc[i] = __builtin_amdgcn_mfma_f32_16x16x32_bf16(aH, bH, acc[i], 0, 0, 0);
            acc[i] = __builtin_amdgcn_mfma_f32_16x16x32_bf16(aL, bH, acc[i], 0, 0, 0);
            acc[i] = __builtin_amdgcn_mfma_f32_16x16x32_bf16(aH, bL, acc[i], 0, 0, 0);
        }
    }

    // epilogue: bias+relu; u (cw-weighted) / v column sums. C/D: col=lane&15, row=quad*4+r
    float c4[4];
    int nb = g * Nc + r0 + mt * 16 + quad * 4;
#pragma unroll
    for (int r = 0; r < 4; ++r) c4[r] = cw[nb + r];
#pragma unroll
    for (int i = 0; i < 4; ++i) {
        int col = (nh * 4 + i) * 16 + (lane & 15);
        float bcol = bias[col];
        float su = 0.f, sv = 0.f;
#pragma unroll
        for (int r = 0; r < 4; ++r) {
            float val = fmaxf(acc[i][r] + bcol, 0.f);
            sv += val;
            su += c4[r] * val;
        }
        su += __shfl_xor(su, 16); sv += __shfl_xor(sv, 16);
        su += __shfl_xor(su, 32); sv += __shfl_xor(sv, 32);
        if (quad == 0) { atomicAdd(&lu[col], su); atomicAdd(&lv[col], sv); }
    }
    __syncthreads();
    if (tid < 256) {
        atomicAdd(&uv[g * 512 + tid], lu[tid]);
        atomicAdd(&uv[g * 512 + 256 + tid], lv[tid]);
    }
}

// ---------------- emb = u/N @ Wl2 + bl2 + v/N @ Wr2. 512 thr, K split 2 ----------------
__global__ __launch_bounds__(512) void emb_kernel(
        const float* __restrict__ uv, const float* __restrict__ Wl2,
        const float* __restrict__ bl2, const float* __restrict__ Wr2,
        float* __restrict__ h) {
    __shared__ float s[512];
    __shared__ float r2[512];
    int g = blockIdx.x, tid = threadIdx.x;
    s[tid] = uv[g * 512 + tid] * (1.0f / Nc);
    __syncthreads();
    int col = tid & 255, p = tid >> 8;
    float val = 0.f;
    if (p == 0) { for (int k = 0; k < 256; ++k) val += s[k] * Wl2[(size_t)k * Hc + col]; }
    else        { for (int k = 0; k < 256; ++k) val += s[256 + k] * Wr2[(size_t)k * Hc + col]; }
    r2[tid] = val;
    __syncthreads();
    if (tid < 256) h[g * Hc + tid] = bl2[tid] + r2[tid] + r2[tid + 256];
}

// ---------------- qkv: token x seg, 512 thr, K split 2 ----------------
__global__ __launch_bounds__(512) void qkv_kernel(
        const float* __restrict__ h, const float* __restrict__ Wqkv,
        const float* __restrict__ bqkv, float* __restrict__ qkv, int l) {
    __shared__ float hr[256];
    __shared__ float r2[512];
    int bid = blockIdx.x;            // 64 tokens * 3 segs
    int gi = bid / 3, seg = bid % 3;
    int tid = threadIdx.x;
    if (tid < 256) hr[tid] = h[gi * Hc + tid];
    __syncthreads();
    int col = seg * 256 + (tid & 255);
    int half = tid >> 8;
    const float* W = Wqkv + (size_t)l * Hc * 768;
    float val = 0.f;
    int k0 = half * 128;
    for (int k = 0; k < 128; ++k) val += hr[k0 + k] * W[(size_t)(k0 + k) * 768 + col];
    r2[tid] = val;
    __syncthreads();
    if (tid < 256) qkv[gi * 768 + col] = bqkv[(size_t)l * 768 + col] + r2[tid] + r2[tid + 256];
}

// ---------------- attn + proj + ln1 -> h1buf. per-token, 512 thr, proj K-split 2 ----------------
#define KVS 516
__global__ __launch_bounds__(512) void apl_kernel(
        const float* __restrict__ h, const float* __restrict__ qkvg,
        const float* __restrict__ Wo, const float* __restrict__ bo,
        const float* __restrict__ s1, const float* __restrict__ b1ln,
        float* __restrict__ h1buf, int l) {
    __shared__ float kv[16 * KVS];
    __shared__ float q[256];
    __shared__ float sc[8][17];
    __shared__ float ctx[256];
    __shared__ float r2[512];
    __shared__ float red[256];
    int t = blockIdx.x, tid = threadIdx.x;
    int b = t >> 4;
    const float* qb = qkvg + (size_t)(b * 16) * 768;
    for (int i = tid; i < 8192; i += 512) {
        int j = i >> 9, d = i & 511;
        kv[j * KVS + d] = qb[(size_t)j * 768 + 256 + d];
    }
    if (tid < 256) q[tid] = qkvg[(size_t)t * 768 + tid];
    __syncthreads();
    if (tid < 128) {
        int hd = tid >> 4, j = tid & 15;
        float s = 0.f;
#pragma unroll
        for (int d = 0; d < 32; ++d) s += q[hd * 32 + d] * kv[j * KVS + hd * 32 + d];
        sc[hd][j] = s * 0.17677669529663687f;
    }
    __syncthreads();
    if (tid < 8) {
        float m = sc[tid][0];
        for (int j = 1; j < 16; ++j) m = fmaxf(m, sc[tid][j]);
        float e[16], sum = 0.f;
        for (int j = 0; j < 16; ++j) { e[j] = expf(sc[tid][j] - m); sum += e[j]; }
        float inv = 1.0f / sum;
        for (int j = 0; j < 16; ++j) sc[tid][j] = e[j] * inv;
    }
    __syncthreads();
    if (tid < 256) {
        int hd = tid >> 5, d = tid & 31;
        float o = 0.f;
#pragma unroll
        for (int j = 0; j < 16; ++j) o += sc[hd][j] * kv[j * KVS + 256 + hd * 32 + d];
        ctx[tid] = o;
    }
    __syncthreads();
    // proj: K split 2 over 512 threads
    int col = tid & 255, half = tid >> 8;
    const float* W = Wo + (size_t)l * 65536;
    float pv = 0.f;
    int k0 = half * 128;
    for (int k = 0; k < 128; ++k) pv += ctx[k0 + k] * W[(size_t)(k0 + k) * 256 + col];
    r2[tid] = pv;
    __syncthreads();
    float val = 0.f;
    if (tid < 256) {
        val = h[(size_t)t * 256 + tid] + bo[(size_t)l * 256 + tid] + r2[tid] + r2[tid + 256];
        red[tid] = val;
    }
    __syncthreads();
    for (int s = 128; s > 0; s >>= 1) { if (tid < s) red[tid] += red[tid + s]; __syncthreads(); }
    float m1 = red[0] * (1.0f / 256.0f);
    __syncthreads();
    float d1 = val - m1;
    if (tid < 256) red[tid] = d1 * d1;
    __syncthreads();
    for (int s = 128; s > 0; s >>= 1) { if (tid < s) red[tid] += red[tid + s]; __syncthreads(); }
    float v1 = red[0] * (1.0f / 256.0f);
    if (tid < 256)
        h1buf[(size_t)t * 256 + tid] =
            d1 * rsqrtf(v1 + EPSc) * s1[(size_t)l * 256 + tid] + b1ln[(size_t)l * 256 + tid];
}

// ---------------- ffn1: (token, colgroup) grid 256, 512 thr, K split 2 ----------------
__global__ __launch_bounds__(512) void ffn1_kernel(
        const float* __restrict__ h1buf, const float* __restrict__ W1,
        const float* __restrict__ bf1, float* __restrict__ fL, int l) {
    __shared__ float hr[256];
    __shared__ float r2[512];
    int bid = blockIdx.x;
    int t = bid >> 2, cg = bid & 3;
    int tid = threadIdx.x;
    if (tid < 256) hr[tid] = h1buf[(size_t)t * 256 + tid];
    __syncthreads();
    int col = cg * 256 + (tid & 255);
    int half = tid >> 8;
    const float* W = W1 + (size_t)l * 262144;
    float val = 0.f;
    int k0 = half * 128;
    for (int k = 0; k < 128; ++k) val += hr[k0 + k] * W[(size_t)(k0 + k) * 1024 + col];
    r2[tid] = val;
    __syncthreads();
    if (tid < 256)
        fL[(size_t)t * 1024 + col] = fmaxf(bf1[(size_t)l * 1024 + col] + r2[tid] + r2[tid + 256], 0.f);
}

// ---------------- ffn2 + ln2 (+fc): per token, 1024 thr, K split 4 ----------------
__global__ __launch_bounds__(1024) void ffn2_ln_kernel(
        float* __restrict__ h, const float* __restrict__ h1buf, const float* __restrict__ fL,
        const float* __restrict__ W2, const float* __restrict__ bf2,
        const float* __restrict__ s2, const float* __restrict__ b2ln,
        const float* __restrict__ fcW, const float* __restrict__ fcb,
        float* __restrict__ out, int l, int last) {
    __shared__ float fs[1024];
    __shared__ float r4[1024];
    __shared__ float red[256];
    int t = blockIdx.x, tid = threadIdx.x;
    fs[tid] = fL[(size_t)t * 1024 + tid];
    __syncthreads();
    int col = tid & 255, kq = tid >> 8;
    const float* W = W2 + (size_t)l * 262144;
    float p = 0.f;
    int k0 = kq * 256;
    for (int k = 0; k < 256; ++k) p += fs[k0 + k] * W[(size_t)(k0 + k) * 256 + col];
    r4[tid] = p;
    __syncthreads();
    float val = 0.f;
    if (tid < 256) {
        val = h1buf[(size_t)t * 256 + tid] + bf2[(size_t)l * 256 + tid]
            + r4[tid] + r4[tid + 256] + r4[tid + 512] + r4[tid + 768];
        red[tid] = val;
    }
    __syncthreads();
    for (int s = 128; s > 0; s >>= 1) { if (tid < s) red[tid] += red[tid + s]; __syncthreads(); }
    float m2 = red[0] * (1.0f / 256.0f);
    __syncthreads();
    float d2 = (tid < 256) ? (val - m2) : 0.f;
    if (tid < 256) red[tid] = d2 * d2;
    __syncthreads();
    for (int s = 128; s > 0; s >>= 1) { if (tid < s) red[tid] += red[tid + s]; __syncthreads(); }
    float var2 = red[0] * (1.0f / 256.0f);
    float hn = 0.f;
    if (tid < 256) {
        hn = d2 * rsqrtf(var2 + EPSc) * s2[(size_t)l * 256 + tid] + b2ln[(size_t)l * 256 + tid];
        h[(size_t)t * 256 + tid] = hn;
    }
    if (last && (t & 15) == 15) {
        __syncthreads();
        if (tid < 256) red[tid] = hn;
        __syncthreads();
        if (tid < 10) {
            int b = t >> 4;
            float fv = fcb[tid];
            for (int k = 0; k < 256; ++k) fv += red[k] * fcW[(size_t)k * 10 + tid];
            out[b * 10 + tid] = fv;
        }
    }
}

extern "C" void kernel_launch(void* const* d_in, const int* in_sizes, int n_in,
                              void* d_out, int out_size, void* d_ws, size_t ws_size,
                              hipStream_t stream) {
    (void)in_sizes; (void)n_in; (void)out_size; (void)ws_size;
    const float* x    = (const float*)d_in[0];
    const int*   ei   = (const int*)d_in[1];
    const float* s1Wl = (const float*)d_in[2];
    const float* s1bl = (const float*)d_in[3];
    const float* s1Wr = (const float*)d_in[4];
    const float* s2Wl = (const float*)d_in[5];
    const float* s2bl = (const float*)d_in[6];
    const float* s2Wr = (const float*)d_in[7];
    const float* Wqkv = (const float*)d_in[8];
    const float* bqkv = (const float*)d_in[9];
    const float* Wo   = (const float*)d_in[10];
    const float* bo   = (const float*)d_in[11];
    const float* ln1s = (const float*)d_in[12];
    const float* ln1b = (const float*)d_in[13];
    const float* W1   = (const float*)d_in[14];
    const float* b1   = (const float*)d_in[15];
    const float* W2   = (const float*)d_in[16];
    const float* b2   = (const float*)d_in[17];
    const float* ln2s = (const float*)d_in[18];
    const float* ln2b = (const float*)d_in[19];
    const float* fcW  = (const float*)d_in[20];
    const float* fcb  = (const float*)d_in[21];

    // workspace layout (total ~3.87 MB)
    char* ws = (char*)d_ws;
    __bf16*         packWH = (__bf16*)(ws + 0);          // 131072
    __bf16*         packWL = (__bf16*)(ws + 131072);     // 131072
    float*          invdeg = (float*)(ws + 262144);      // 262144
    float*          cw     = (float*)(ws + 524288);      // 262144
    int*            off    = (int*)(ws + 786432);        // 264192
    unsigned short* elist  = (unsigned short*)(ws + 1050624); // 2097152
    float*          uv     = (float*)(ws + 3147776);     // 131072
    float*          h      = (float*)(ws + 3278848);     // 65536
    float*          qkvg   = (float*)(ws + 3344384);     // 196608
    float*          h1buf  = (float*)(ws + 3540992);     // 65536
    float*          fLbuf  = (float*)(ws + 3606528);     // 262144
                                                         // end = 3868672

    pack_w_kernel<<<128, 512, 0, stream>>>(s1Wl, s1Wr, packWH, packWL);
    csr_kernel<<<Gc, 1024, 0, stream>>>(ei, invdeg, cw, off, elist, uv);
    sage_kernel<<<Gc * 32, 512, 0, stream>>>(x, elist, off, invdeg, cw, packWH, packWL, s1bl, uv);
    emb_kernel<<<Gc, 512, 0, stream>>>(uv, s2Wl, s2bl, s2Wr, h);
    for (int l = 0; l < Lc; ++l) {
        qkv_kernel<<<Gc * 3, 512, 0, stream>>>(h, Wqkv, bqkv, qkvg, l);
        apl_kernel<<<Gc, 512, 0, stream>>>(h, qkvg, Wo, bo, ln1s, ln1b, h1buf, l);
        ffn1_kernel<<<Gc * 4, 512, 0, stream>>>(h1buf, W1, b1, fLbuf, l);
        ffn2_ln_kernel<<<Gc, 1024, 0, stream>>>(h, h1buf, fLbuf, W2, b2, ln2s, ln2b,
                                                fcW, fcb, (float*)d_out, l, l == Lc - 1);
    }
}